// Round 9
// baseline (222.496 us; speedup 1.0000x reference)
//
#include <hip/hip_runtime.h>

// CRF forward (logZ) — B=1024 chains, T=256 steps, N=64 labels.
// One block (4 waves) per chain; lane k owns label k in EVERY wave.
// j-split: wave w owns j in [16w,16w+16) of the dot
//   s_k = sum_j u_j * E[j,k]
// Per step per wave: pack u to bf16 pairs, 8 readlanes + 8 v_dot2_f32_bf16
// (R6-verified numerics), 1 LDS partial write, 1 __syncthreads, 4 reads+add.
// Ping-pong partial buffers make one barrier/step WAR-safe.
// 4 waves/SIMD from 4 different chains hide each other's stalls.
// u'(t) = s * (R*ee); R = rcp(u0), Pm *= u0 side-chain; frexp renorm/group.

#define CRF_B 1024
#define CRF_T 256
#define CRF_N 64

typedef __bf16 bf16x2 __attribute__((ext_vector_type(2)));

__device__ __forceinline__ float rl0(float x) {
    return __int_as_float(__builtin_amdgcn_readfirstlane(__float_as_int(x)));
}
__device__ __forceinline__ float rlanef(float x, int j) {
    return __int_as_float(__builtin_amdgcn_readlane(__float_as_int(x), j));
}

__device__ __forceinline__ float wave_lse(float v) {
    float m = v;
    #pragma unroll
    for (int off = 1; off < 64; off <<= 1) m = fmaxf(m, __shfl_xor(m, off));
    float s = __expf(v - m);
    #pragma unroll
    for (int off = 1; off < 64; off <<= 1) s += __shfl_xor(s, off);
    return m + __logf(s);
}

// f32 -> bf16 RNE, low 16 bits
__device__ __forceinline__ unsigned bf16_rne(float f) {
    unsigned u = __float_as_uint(f);
    return (u + 0x7FFFu + ((u >> 16) & 1u)) >> 16;
}

// lane L: pack(bf16(u_L), bf16(u_{L^1})) — valid (even,odd) pairs on EVEN lanes
__device__ __forceinline__ unsigned pack_pairs(float u) {
    unsigned pa = __float_as_uint(u) + 0x8000u;                 // cheap RN
    unsigned pb = (unsigned)__builtin_amdgcn_update_dpp(
        0, (int)pa, 0xB1 /*quad_perm [1,0,3,2]*/, 0xF, 0xF, false);
    return __builtin_amdgcn_perm(pb, pa, 0x07060302);
}

__device__ __forceinline__ float dot2bf(unsigned a, unsigned b, float c) {
#if __has_builtin(__builtin_amdgcn_fdot2_f32_bf16)
    return __builtin_amdgcn_fdot2_f32_bf16(__builtin_bit_cast(bf16x2, a),
                                           __builtin_bit_cast(bf16x2, b),
                                           c, false);
#else
    float d = c;
    asm("v_dot2_f32_bf16 %0, %1, %2, %0" : "+v"(d) : "v"(a), "v"(b));
    return d;
#endif
}

__launch_bounds__(256, 4)
__global__ void crf_fwd_kernel(const float* __restrict__ emit,
                               const float* __restrict__ trans,
                               const float* __restrict__ strans,
                               const float* __restrict__ etrans,
                               const unsigned char* __restrict__ mask_u8,
                               float* __restrict__ out)
{
    const int tid  = threadIdx.x;
    const int lane = tid & 63;
    const int wv   = tid >> 6;                                  // 0..3
    const int wq   = __builtin_amdgcn_readfirstlane(wv);        // SGPR copy
    const int b    = blockIdx.x;

    __shared__ float pbuf[2][4][CRF_N];   // [parity][wave][lane]

    // ---------- register-only preprocess (redundant per wave) ----------
    float rowlse_v;
    {
        const float* rowp = trans + lane * CRF_N;
        float m = -1e30f;
        #pragma unroll 8
        for (int k = 0; k < CRF_N; ++k) m = fmaxf(m, rowp[k]);
        float s = 0.f;
        #pragma unroll 8
        for (int k = 0; k < CRF_N; ++k) s += __expf(rowp[k] - m);
        rowlse_v = m + __logf(s);
    }

    // global column max for column k = lane
    float cmx = -1e30f;
    #pragma unroll
    for (int j = 0; j < CRF_N; ++j)
        cmx = fmaxf(cmx, trans[j * CRF_N + lane] - rlanef(rowlse_v, j));

    // this wave's E pairs: Epk[i] = (E[16w+2i][lane], E[16w+2i+1][lane])
    unsigned Epk[8];
    #pragma unroll
    for (int i = 0; i < 8; ++i) {
        int j0 = 16 * wq + 2 * i;
        float e0 = __expf(trans[j0 * CRF_N + lane]      - rlanef(rowlse_v, j0)     - cmx);
        float e1 = __expf(trans[(j0 + 1) * CRF_N + lane] - rlanef(rowlse_v, j0 + 1) - cmx);
        Epk[i] = bf16_rne(e0) | (bf16_rne(e1) << 16);
    }

    const float sn = wave_lse(strans[lane]);

    // ---- sequence length from mask (dtype-adaptive: bool bytes vs int32) ----
    int len;
    {
        int c8 = 0;
        #pragma unroll
        for (int q = 0; q < 4; ++q)
            c8 += (mask_u8[(size_t)b * CRF_T + q * 64 + lane] != 0) ? 1 : 0;
        for (int off = 1; off < 64; off <<= 1) c8 += __shfl_xor(c8, off);
        if (c8 >= 128) {
            len = c8;       // genuine bool bytes (len in [128,256])
        } else {
            const int* mi = (const int*)mask_u8;
            int ci = 0;
            #pragma unroll
            for (int q = 0; q < 4; ++q)
                ci += (mi[(size_t)b * CRF_T + q * 64 + lane] != 0) ? 1 : 0;
            for (int off = 1; off < 64; off <<= 1) ci += __shfl_xor(ci, off);
            len = ci;
        }
    }

    const float* eb = emit + (size_t)b * CRF_T * CRF_N;

    // ---------- init (t = 0): all waves hold the full u vector ----------
    float alpha0 = (strans[lane] - sn) + eb[lane];
    float c0 = rl0(alpha0);
    float u  = __expf(alpha0 - c0);   // lane 0: u = 1
    float R  = 1.0f;                  // rcp of previous step's u0
    float Pm = 1.0f;                  // running product of u0 (mantissa)
    int   Eacc = 0;                   // running exponent (base 2)

    // one step (parity P): partial dot over this wave's 16 j's
#define CRF_STEP(EE, EE0, P)                                                 \
    {                                                                        \
        unsigned upi = pack_pairs(u);                                        \
        float ree = R * (EE);                                                \
        float sc0 = R * (EE0);                                               \
        float a0 = 0.f, a1 = 0.f;                                            \
        _Pragma("unroll")                                                    \
        for (int i = 0; i < 8; i += 2) {                                     \
            unsigned x0 = (unsigned)__builtin_amdgcn_readlane(               \
                (int)upi, 16 * wq + 2 * i);                                  \
            unsigned x1 = (unsigned)__builtin_amdgcn_readlane(               \
                (int)upi, 16 * wq + 2 * i + 2);                              \
            a0 = dot2bf(x0, Epk[i],     a0);                                 \
            a1 = dot2bf(x1, Epk[i + 1], a1);                                 \
        }                                                                    \
        pbuf[(P)][wv][lane] = a0 + a1;                                       \
        __syncthreads();                                                     \
        float s = (pbuf[(P)][0][lane] + pbuf[(P)][1][lane])                  \
                + (pbuf[(P)][2][lane] + pbuf[(P)][3][lane]);                 \
        float s0 = rl0(s);                                                   \
        u = s * ree;                                                         \
        float u0 = s0 * sc0;                                                 \
        R = __builtin_amdgcn_rcpf(u0);                                       \
        Pm *= u0;                                                            \
    }

    // ---------- main loop: groups of 4 with emission prefetch ----------
    float eN[4], eeC[4], ee0C[4];
    #pragma unroll
    for (int d = 0; d < 4; ++d) eN[d] = eb[(size_t)(1 + d) * CRF_N + lane];
    #pragma unroll
    for (int d = 0; d < 4; ++d) eeC[d] = __expf(eN[d] + cmx);
    #pragma unroll
    for (int d = 0; d < 4; ++d) ee0C[d] = rl0(eeC[d]);

    int t0 = 1;
    while (t0 + 4 <= len) {
        #pragma unroll
        for (int d = 0; d < 4; ++d) {
            int ti = t0 + 4 + d;
            ti = (ti < len) ? ti : (len - 1);
            eN[d] = eb[(size_t)ti * CRF_N + lane];
        }
        CRF_STEP(eeC[0], ee0C[0], 1); CRF_STEP(eeC[1], ee0C[1], 0);
        CRF_STEP(eeC[2], ee0C[2], 1); CRF_STEP(eeC[3], ee0C[3], 0);
        {
            int ex;
            Pm = frexpf(Pm, &ex);
            Eacc += ex;
        }
        #pragma unroll
        for (int d = 0; d < 4; ++d) eeC[d] = __expf(eN[d] + cmx);
        #pragma unroll
        for (int d = 0; d < 4; ++d) ee0C[d] = rl0(eeC[d]);
        t0 += 4;
    }
    {
        const int nrem = len - t0;   // block-uniform, < 4
        if (nrem > 0) { CRF_STEP(eeC[0], ee0C[0], 1); }
        if (nrem > 1) { CRF_STEP(eeC[1], ee0C[1], 0); }
        if (nrem > 2) { CRF_STEP(eeC[2], ee0C[2], 1); }
    }
#undef CRF_STEP

    // ---------- final lse over labels + batch-sum (all waves identical) ----------
    const float en = wave_lse(etrans[lane]);
    float Lacc = c0 + 0.6931471805599453f * (float)Eacc + __logf(Pm);
    float v = Lacc + __logf(u * R) + (etrans[lane] - en);
    float m = v;
    #pragma unroll
    for (int off = 1; off < 64; off <<= 1) m = fmaxf(m, __shfl_xor(m, off));
    float sum = __expf(v - m);
    #pragma unroll
    for (int off = 1; off < 64; off <<= 1) sum += __shfl_xor(sum, off);

    if (tid == 0) {
        atomicAdd(out, m + __logf(sum));
    }
}

extern "C" void kernel_launch(void* const* d_in, const int* in_sizes, int n_in,
                              void* d_out, int out_size, void* d_ws, size_t ws_size,
                              hipStream_t stream) {
    const float* emit   = (const float*)d_in[0];
    const float* trans  = (const float*)d_in[1];
    const float* strans = (const float*)d_in[2];
    const float* etrans = (const float*)d_in[3];
    const unsigned char* mask = (const unsigned char*)d_in[4];
    float* out = (float*)d_out;

    hipMemsetAsync(out, 0, sizeof(float), stream);
    crf_fwd_kernel<<<dim3(CRF_B), dim3(256), 0, stream>>>(
        emit, trans, strans, etrans, mask, out);
}

// Round 10
// 198.782 us; speedup vs baseline: 1.1193x; 1.1193x over previous
//
#include <hip/hip_runtime.h>

// CRF forward (logZ) — B=1024 chains, T=256 steps, N=64 labels.
// One 64-lane wave per chain, wave-private hot loop (no barriers).
// Per step: 64x64 log-matvec via 8x v_mfma_f32_16x16x32_bf16 with A built so
// EVERY row = u  ->  every D reg holds s[cm]  (layouts self-calibrated with
// R8's probe machinery, which measured absmax 0.0).
// Feedback D->A with NO LDS round trip: 16 ds_bpermute (addresses are
// preprocess constants from a quad/cm table) + 8 in-register bf16 packs.
// u'(t) = s * (R*ee); R = rcp(u0), Pm *= u0 side-chain; frexp renorm/group.

#define CRF_B 1024
#define CRF_T 256
#define CRF_N 64

typedef short s16x8 __attribute__((ext_vector_type(8)));
typedef float f32x4 __attribute__((ext_vector_type(4)));
typedef int   i32x4 __attribute__((ext_vector_type(4)));

#define MFMA_BF16 __builtin_amdgcn_mfma_f32_16x16x32_bf16

__device__ __forceinline__ float rl0(float x) {
    return __int_as_float(__builtin_amdgcn_readfirstlane(__float_as_int(x)));
}
__device__ __forceinline__ float rlanef(float x, int j) {
    return __int_as_float(__builtin_amdgcn_readlane(__float_as_int(x), j));
}
__device__ __forceinline__ float bperm_f(float v, int srclane) {
    return __int_as_float(
        __builtin_amdgcn_ds_bpermute(srclane << 2, __float_as_int(v)));
}
__device__ __forceinline__ float bperm_fa(int byteaddr, float v) {
    return __int_as_float(
        __builtin_amdgcn_ds_bpermute(byteaddr, __float_as_int(v)));
}
__device__ __forceinline__ float wave_lse(float v) {
    float m = v;
    #pragma unroll
    for (int off = 1; off < 64; off <<= 1) m = fmaxf(m, __shfl_xor(m, off));
    float s = __expf(v - m);
    #pragma unroll
    for (int off = 1; off < 64; off <<= 1) s += __shfl_xor(s, off);
    return m + __logf(s);
}

// f32 -> bf16 RNE (static E table)
__device__ __forceinline__ unsigned bf16_rne(float f) {
    unsigned u = __float_as_uint(f);
    return (u + 0x7FFFu + ((u >> 16) & 1u)) >> 16;
}
// exact bf16 bits for small integers / powers of two
__device__ __forceinline__ unsigned bfb(float f) {
    return __float_as_uint(f) >> 16;
}
// pack two f32 into one bf16-pair word (cheap RN; R6/R8-verified class)
__device__ __forceinline__ int pk2(float x, float y) {
    unsigned ax = __float_as_uint(x) + 0x8000u;
    unsigned ay = __float_as_uint(y) + 0x8000u;
    return (int)__builtin_amdgcn_perm(ay, ax, 0x07060302);
}

__launch_bounds__(64, 1)
__attribute__((amdgpu_waves_per_eu(1, 1)))
__global__ void crf_fwd_kernel(const float* __restrict__ emit,
                               const float* __restrict__ trans,
                               const float* __restrict__ strans,
                               const float* __restrict__ etrans,
                               const unsigned char* __restrict__ mask_u8,
                               float* __restrict__ out)
{
    const int lane = threadIdx.x;      // 0..63
    const int b    = blockIdx.x;
    const int c    = lane & 15;        // physical B-column slot group
    const int q    = lane >> 4;

    __shared__ int lw[CRF_N];          // lw[q*16 + cm] = lane id

    // ---------- rowlse (row = lane) ----------
    float rowlse_v;
    {
        const float* rowp = trans + lane * CRF_N;
        float m = -1e30f;
        #pragma unroll 8
        for (int k = 0; k < CRF_N; ++k) m = fmaxf(m, rowp[k]);
        float s = 0.f;
        #pragma unroll 8
        for (int k = 0; k < CRF_N; ++k) s += __expf(rowp[k] - m);
        rowlse_v = m + __logf(s);
    }

    // ---------- layout probes (R8-verified) ----------
    const f32x4 zz = {0.f, 0.f, 0.f, 0.f};

    // colmap: A = ones, B slots = lane&15  ->  D = 32*col  (reg 0 everywhere)
    int cm;
    {
        unsigned ob = bfb(1.0f);
        int ow = (int)(ob | (ob << 16));
        i32x4 av = {ow, ow, ow, ow};
        unsigned cb = bfb((float)c);
        int cw = (int)(cb | (cb << 16));
        i32x4 bv = {cw, cw, cw, cw};
        f32x4 pr = MFMA_BF16(__builtin_bit_cast(s16x8, av),
                             __builtin_bit_cast(s16x8, bv), zz, 0, 0, 0);
        cm = ((int)(pr[0] * 0.03125f + 0.5f)) & 15;
    }

    // pairing: A slot (q,j) = 8q+j; B slot j0 = 32^q -> D digits give pi
    int rpi[8];
    {
        i32x4 aenc;
        #pragma unroll
        for (int p = 0; p < 4; ++p)
            aenc[p] = (int)(bfb((float)(8 * q + 2 * p)) |
                            (bfb((float)(8 * q + 2 * p + 1)) << 16));
        s16x8 Aenc = __builtin_bit_cast(s16x8, aenc);
        float p32   = (float)(1 << (5 * q));
        float p32in = __builtin_amdgcn_rcpf(p32);
        unsigned wb = bfb(p32);
        #pragma unroll
        for (int j0 = 0; j0 < 8; ++j0) {
            i32x4 bv = {0, 0, 0, 0};
            bv[j0 >> 1] = (j0 & 1) ? (int)(wb << 16) : (int)wb;
            f32x4 pr = MFMA_BF16(Aenc, __builtin_bit_cast(s16x8, bv),
                                 zz, 0, 0, 0);
            rpi[j0] = ((int)floorf(pr[0] * p32in)) & 31;
        }
    }

    // ---------- source-lane table + bpermute addresses ----------
    lw[q * 16 + cm] = lane;            // bijection within each quad
    __syncthreads();
    int addrA[8];
    #pragma unroll
    for (int j = 0; j < 8; ++j) {
        int k = 8 * q + j;             // canonical slot index (0..31)
        int n = k >> 4, cs = k & 15;
        addrA[j] = lw[(2 * n) * 16 + cs] << 2;   // source quad 2n
    }
    const bool quadlow = (q < 2);

    // ---------- column maxes: physical cols (B build) and own cols (ee) ----------
    float cmxB[4], cmxW[4];
    #pragma unroll
    for (int n = 0; n < 4; ++n) { cmxB[n] = -1e30f; cmxW[n] = -1e30f; }
    for (int j = 0; j < CRF_N; ++j) {
        float rl = rlanef(rowlse_v, j);
        #pragma unroll
        for (int n = 0; n < 4; ++n) {
            cmxB[n] = fmaxf(cmxB[n], trans[j * CRF_N + 16 * n + c]  - rl);
            cmxW[n] = fmaxf(cmxW[n], trans[j * CRF_N + 16 * n + cm] - rl);
        }
    }

    // ---------- B-frags with probed row pairing (R8-verified) ----------
    s16x8 Bf[2][4];
    #pragma unroll
    for (int h = 0; h < 2; ++h) {
        #pragma unroll
        for (int n = 0; n < 4; ++n) {
            i32x4 acc;
            #pragma unroll
            for (int p = 0; p < 4; ++p) {
                int r0 = 32 * h + rpi[2 * p];
                int r1 = 32 * h + rpi[2 * p + 1];
                float rls0 = bperm_f(rowlse_v, r0);
                float rls1 = bperm_f(rowlse_v, r1);
                float e0 = __expf(trans[r0 * CRF_N + 16 * n + c] - rls0 - cmxB[n]);
                float e1 = __expf(trans[r1 * CRF_N + 16 * n + c] - rls1 - cmxB[n]);
                acc[p] = (int)(bf16_rne(e0) | (bf16_rne(e1) << 16));
            }
            Bf[h][n] = __builtin_bit_cast(s16x8, acc);
        }
    }

    const float sn = wave_lse(strans[lane]);

    // ---- sequence length from mask (dtype-adaptive: bool bytes vs int32) ----
    int len;
    {
        int c8 = 0;
        #pragma unroll
        for (int qq = 0; qq < 4; ++qq)
            c8 += (mask_u8[(size_t)b * CRF_T + qq * 64 + lane] != 0) ? 1 : 0;
        for (int off = 1; off < 64; off <<= 1) c8 += __shfl_xor(c8, off);
        if (c8 >= 128) {
            len = c8;
        } else {
            const int* mi = (const int*)mask_u8;
            int ci = 0;
            #pragma unroll
            for (int qq = 0; qq < 4; ++qq)
                ci += (mi[(size_t)b * CRF_T + qq * 64 + lane] != 0) ? 1 : 0;
            for (int off = 1; off < 64; off <<= 1) ci += __shfl_xor(ci, off);
            len = ci;
        }
    }

    const float* eb = emit + (size_t)b * CRF_T * CRF_N;

    // ---------- init (t = 0) ----------
    float un[4];
    float R = 1.0f, Pm = 1.0f;
    int Eacc = 0;
    float c0;
    {
        float a0[4];
        #pragma unroll
        for (int n = 0; n < 4; ++n)
            a0[n] = (strans[16 * n + cm] - sn) + eb[16 * n + cm];
        c0 = rl0(a0[0]);
        #pragma unroll
        for (int n = 0; n < 4; ++n) un[n] = __expf(a0[n] - c0);
    }

    s16x8 A0f, A1f;

    // rebuild A-frags from un via bpermute (no LDS, no barrier)
#define PUB()                                                                \
    {                                                                        \
        float Xa = quadlow ? un[0] : un[1];                                  \
        float Xb = quadlow ? un[2] : un[3];                                  \
        float a0v = bperm_fa(addrA[0], Xa);                                  \
        float a1v = bperm_fa(addrA[1], Xa);                                  \
        float a2v = bperm_fa(addrA[2], Xa);                                  \
        float a3v = bperm_fa(addrA[3], Xa);                                  \
        float a4v = bperm_fa(addrA[4], Xa);                                  \
        float a5v = bperm_fa(addrA[5], Xa);                                  \
        float a6v = bperm_fa(addrA[6], Xa);                                  \
        float a7v = bperm_fa(addrA[7], Xa);                                  \
        float b0v = bperm_fa(addrA[0], Xb);                                  \
        float b1v = bperm_fa(addrA[1], Xb);                                  \
        float b2v = bperm_fa(addrA[2], Xb);                                  \
        float b3v = bperm_fa(addrA[3], Xb);                                  \
        float b4v = bperm_fa(addrA[4], Xb);                                  \
        float b5v = bperm_fa(addrA[5], Xb);                                  \
        float b6v = bperm_fa(addrA[6], Xb);                                  \
        float b7v = bperm_fa(addrA[7], Xb);                                  \
        i32x4 wa = {pk2(a0v, a1v), pk2(a2v, a3v),                            \
                    pk2(a4v, a5v), pk2(a6v, a7v)};                           \
        i32x4 wb2 = {pk2(b0v, b1v), pk2(b2v, b3v),                           \
                     pk2(b4v, b5v), pk2(b6v, b7v)};                          \
        A0f = __builtin_bit_cast(s16x8, wa);                                 \
        A1f = __builtin_bit_cast(s16x8, wb2);                                \
    }

    PUB();

    // one step: 8 MFMA -> scale -> bpermute feedback
#define CRF_STEP(EE)                                                         \
    {                                                                        \
        float Ree0 = R * (EE)[0];                                            \
        float Ree1 = R * (EE)[1];                                            \
        float Ree2 = R * (EE)[2];                                            \
        float Ree3 = R * (EE)[3];                                            \
        f32x4 p0 = MFMA_BF16(A0f, Bf[0][0], zz, 0, 0, 0);                    \
        f32x4 p1 = MFMA_BF16(A0f, Bf[0][1], zz, 0, 0, 0);                    \
        f32x4 p2 = MFMA_BF16(A0f, Bf[0][2], zz, 0, 0, 0);                    \
        f32x4 p3 = MFMA_BF16(A0f, Bf[0][3], zz, 0, 0, 0);                    \
        f32x4 q0 = MFMA_BF16(A1f, Bf[1][0], p0, 0, 0, 0);                    \
        f32x4 q1 = MFMA_BF16(A1f, Bf[1][1], p1, 0, 0, 0);                    \
        f32x4 q2 = MFMA_BF16(A1f, Bf[1][2], p2, 0, 0, 0);                    \
        f32x4 q3 = MFMA_BF16(A1f, Bf[1][3], p3, 0, 0, 0);                    \
        un[0] = q0[0] * Ree0;                                                \
        un[1] = q1[0] * Ree1;                                                \
        un[2] = q2[0] * Ree2;                                                \
        un[3] = q3[0] * Ree3;                                                \
        float u0 = rl0(un[0]);                                               \
        R = __builtin_amdgcn_rcpf(u0);                                       \
        Pm *= u0;                                                            \
        PUB();                                                               \
    }

    // ---------- main loop: groups of 4 with emission prefetch ----------
    float eN[4][4], eeC[4][4];
    #pragma unroll
    for (int d = 0; d < 4; ++d)
        #pragma unroll
        for (int n = 0; n < 4; ++n)
            eN[d][n] = eb[(size_t)(1 + d) * CRF_N + 16 * n + cm];
    #pragma unroll
    for (int d = 0; d < 4; ++d)
        #pragma unroll
        for (int n = 0; n < 4; ++n)
            eeC[d][n] = __expf(eN[d][n] + cmxW[n]);

    int t0 = 1;
    while (t0 + 4 <= len) {
        #pragma unroll
        for (int d = 0; d < 4; ++d) {
            int ti = t0 + 4 + d;
            ti = (ti < len) ? ti : (len - 1);
            #pragma unroll
            for (int n = 0; n < 4; ++n)
                eN[d][n] = eb[(size_t)ti * CRF_N + 16 * n + cm];
        }
        CRF_STEP(eeC[0]); CRF_STEP(eeC[1]);
        CRF_STEP(eeC[2]); CRF_STEP(eeC[3]);
        {
            int ex;
            Pm = frexpf(Pm, &ex);
            Eacc += ex;
        }
        #pragma unroll
        for (int d = 0; d < 4; ++d)
            #pragma unroll
            for (int n = 0; n < 4; ++n)
                eeC[d][n] = __expf(eN[d][n] + cmxW[n]);
        t0 += 4;
    }
    {
        const int nrem = len - t0;   // wave-uniform, < 4
        #pragma unroll
        for (int d = 0; d < 4; ++d) {
            if (d >= nrem) break;
            CRF_STEP(eeC[d]);
        }
    }
#undef CRF_STEP
#undef PUB

    // ---------- final lse over labels + batch-sum ----------
    // quad-0 lanes cover each column group exactly once (16 lanes x 4 n = 64)
    const float en = wave_lse(etrans[lane]);
    float Lacc = c0 + 0.6931471805599453f * (float)Eacc + __logf(Pm);
    float vm = -1e30f;
    float v4[4];
    #pragma unroll
    for (int n = 0; n < 4; ++n) {
        v4[n] = Lacc + __logf(un[n] * R) + (etrans[16 * n + cm] - en);
        vm = fmaxf(vm, v4[n]);
    }
    float vs = 0.f;
    #pragma unroll
    for (int n = 0; n < 4; ++n) vs += __expf(v4[n] - vm);
    float Lf = (q == 0) ? (vm + __logf(vs)) : -1e30f;

    float m = Lf;
    #pragma unroll
    for (int off = 1; off < 64; off <<= 1) m = fmaxf(m, __shfl_xor(m, off));
    float sum = __expf(Lf - m);
    #pragma unroll
    for (int off = 1; off < 64; off <<= 1) sum += __shfl_xor(sum, off);

    if (lane == 0) {
        atomicAdd(out, m + __logf(sum));
    }
}

extern "C" void kernel_launch(void* const* d_in, const int* in_sizes, int n_in,
                              void* d_out, int out_size, void* d_ws, size_t ws_size,
                              hipStream_t stream) {
    const float* emit   = (const float*)d_in[0];
    const float* trans  = (const float*)d_in[1];
    const float* strans = (const float*)d_in[2];
    const float* etrans = (const float*)d_in[3];
    const unsigned char* mask = (const unsigned char*)d_in[4];
    float* out = (float*)d_out;

    hipMemsetAsync(out, 0, sizeof(float), stream);
    crf_fwd_kernel<<<dim3(CRF_B), dim3(64), 0, stream>>>(
        emit, trans, strans, etrans, mask, out);
}

// Round 11
// 168.512 us; speedup vs baseline: 1.3204x; 1.1796x over previous
//
#include <hip/hip_runtime.h>

// CRF forward (logZ) — B=1024, T=256, N=64. Meet-in-the-middle:
//   forward alpha: t = 1..127   (len>=128 -> never masked, no mask logic)
//   backward beta: t = len-1..128  (len-128 steps, avg ~64)
//   logZ_b = lse_j(alpha_127[j] + beta_127[j])   (combine kernel)
// 2048 waves = 2/SIMD -> independent waves hide each other's stalls.
// Per-step body = R6's verified readlane+v_dot2_f32_bf16 dot (absmax 0.0).
// Backward uses E'[j,k] = exp(tn[j,k]) (row-stochastic, entries <= 1,
// no shift needed); emission factor multiplies the state BEFORE broadcast.

#define CRF_B 1024
#define CRF_T 256
#define CRF_N 64
#define WS_BF_OFF 65536   // floats: bf starts after 1024*64 af floats

typedef __bf16 bf16x2 __attribute__((ext_vector_type(2)));

__device__ __forceinline__ float rl0(float x) {
    return __int_as_float(__builtin_amdgcn_readfirstlane(__float_as_int(x)));
}
__device__ __forceinline__ float rlanef(float x, int j) {
    return __int_as_float(__builtin_amdgcn_readlane(__float_as_int(x), j));
}

__device__ __forceinline__ float wave_lse(float v) {
    float m = v;
    #pragma unroll
    for (int off = 1; off < 64; off <<= 1) m = fmaxf(m, __shfl_xor(m, off));
    float s = __expf(v - m);
    #pragma unroll
    for (int off = 1; off < 64; off <<= 1) s += __shfl_xor(s, off);
    return m + __logf(s);
}

// f32 -> bf16 RNE, low 16 bits
__device__ __forceinline__ unsigned bf16_rne(float f) {
    unsigned u = __float_as_uint(f);
    return (u + 0x7FFFu + ((u >> 16) & 1u)) >> 16;
}

// lane L: pack(bf16(u_L), bf16(u_{L^1})) — valid (even,odd) pairs on EVEN lanes
__device__ __forceinline__ unsigned pack_pairs(float u) {
    unsigned pa = __float_as_uint(u) + 0x8000u;                 // cheap RN
    unsigned pb = (unsigned)__builtin_amdgcn_update_dpp(
        0, (int)pa, 0xB1 /*quad_perm [1,0,3,2]*/, 0xF, 0xF, false);
    return __builtin_amdgcn_perm(pb, pa, 0x07060302);
}

__device__ __forceinline__ float dot2bf(unsigned a, unsigned b, float c) {
#if __has_builtin(__builtin_amdgcn_fdot2_f32_bf16)
    return __builtin_amdgcn_fdot2_f32_bf16(__builtin_bit_cast(bf16x2, a),
                                           __builtin_bit_cast(bf16x2, b),
                                           c, false);
#else
    float d = c;
    asm("v_dot2_f32_bf16 %0, %1, %2, %0" : "+v"(d) : "v"(a), "v"(b));
    return d;
#endif
}

// 64-term broadcast dot: s = sum_m dot2(pair_m(upi), Pk[m])
__device__ __forceinline__ float bdot64(unsigned upi, const unsigned* Pk) {
    float a0 = 0.f, a1 = 0.f, a2 = 0.f, a3 = 0.f;
    #pragma unroll
    for (int m2 = 0; m2 < 32; m2 += 4) {
        unsigned w0 = (unsigned)__builtin_amdgcn_readlane((int)upi, 2 * m2 + 0);
        unsigned w1 = (unsigned)__builtin_amdgcn_readlane((int)upi, 2 * m2 + 2);
        unsigned w2 = (unsigned)__builtin_amdgcn_readlane((int)upi, 2 * m2 + 4);
        unsigned w3 = (unsigned)__builtin_amdgcn_readlane((int)upi, 2 * m2 + 6);
        a0 = dot2bf(w0, Pk[m2 + 0], a0);
        a1 = dot2bf(w1, Pk[m2 + 1], a1);
        a2 = dot2bf(w2, Pk[m2 + 2], a2);
        a3 = dot2bf(w3, Pk[m2 + 3], a3);
    }
    return (a0 + a1) + (a2 + a3);
}

__launch_bounds__(64)
__global__ void crf_fb_kernel(const float* __restrict__ emit,
                              const float* __restrict__ trans,
                              const float* __restrict__ strans,
                              const float* __restrict__ etrans,
                              const unsigned char* __restrict__ mask_u8,
                              float* __restrict__ ws)
{
    const int lane = threadIdx.x;          // 0..63
    const int bid  = blockIdx.x;
    const int b    = bid >> 1;
    const bool fwd = (bid & 1) == 0;

    // ---------- rowlse (row = lane) ----------
    float rowlse_v;
    {
        const float* rowp = trans + lane * CRF_N;
        float m = -1e30f;
        #pragma unroll 8
        for (int k = 0; k < CRF_N; ++k) m = fmaxf(m, rowp[k]);
        float s = 0.f;
        #pragma unroll 8
        for (int k = 0; k < CRF_N; ++k) s += __expf(rowp[k] - m);
        rowlse_v = m + __logf(s);
    }

    const float* eb = emit + (size_t)b * CRF_T * CRF_N;

    if (fwd) {
        // ================= FORWARD: alpha_0 -> alpha_127 =================
        // E[j,k] = exp(tn[j,k] - cmx_k); this lane holds column k=lane pairs.
        float cmx = -1e30f;
        #pragma unroll
        for (int j = 0; j < CRF_N; ++j)
            cmx = fmaxf(cmx, trans[j * CRF_N + lane] - rlanef(rowlse_v, j));
        unsigned Epk[32];
        #pragma unroll
        for (int m = 0; m < 32; ++m) {
            float e0 = __expf(trans[(2 * m)     * CRF_N + lane] - rlanef(rowlse_v, 2 * m)     - cmx);
            float e1 = __expf(trans[(2 * m + 1) * CRF_N + lane] - rlanef(rowlse_v, 2 * m + 1) - cmx);
            Epk[m] = bf16_rne(e0) | (bf16_rne(e1) << 16);
        }

        const float sn = wave_lse(strans[lane]);

        float alpha0 = (strans[lane] - sn) + eb[lane];
        float c0 = rl0(alpha0);
        float u  = __expf(alpha0 - c0);
        float R  = 1.0f, Pm = 1.0f;
        int   Eacc = 0;

#define FWD_STEP(EE, EE0)                                                    \
        {                                                                    \
            unsigned upi = pack_pairs(u);                                    \
            float ree = R * (EE);                                            \
            float sc0 = R * (EE0);                                           \
            float s = bdot64(upi, Epk);                                      \
            float s0 = rl0(s);                                               \
            u = s * ree;                                                     \
            float u0 = s0 * sc0;                                             \
            R = __builtin_amdgcn_rcpf(u0);                                   \
            Pm *= u0;                                                        \
        }

        float eN[4], eeC[4], ee0C[4];
        #pragma unroll
        for (int d = 0; d < 4; ++d) eN[d] = eb[(size_t)(1 + d) * CRF_N + lane];
        #pragma unroll
        for (int d = 0; d < 4; ++d) eeC[d] = __expf(eN[d] + cmx);
        #pragma unroll
        for (int d = 0; d < 4; ++d) ee0C[d] = rl0(eeC[d]);

        int t0 = 1;
        while (t0 + 4 <= 128) {
            #pragma unroll
            for (int d = 0; d < 4; ++d) {
                int ti = t0 + 4 + d;
                ti = (ti < 128) ? ti : 127;
                eN[d] = eb[(size_t)ti * CRF_N + lane];
            }
            FWD_STEP(eeC[0], ee0C[0]); FWD_STEP(eeC[1], ee0C[1]);
            FWD_STEP(eeC[2], ee0C[2]); FWD_STEP(eeC[3], ee0C[3]);
            { int ex; Pm = frexpf(Pm, &ex); Eacc += ex; }
            #pragma unroll
            for (int d = 0; d < 4; ++d) eeC[d] = __expf(eN[d] + cmx);
            #pragma unroll
            for (int d = 0; d < 4; ++d) ee0C[d] = rl0(eeC[d]);
            t0 += 4;
        }
        // tail: t = 125,126,127  (t0 == 125 here)
        FWD_STEP(eeC[0], ee0C[0]);
        FWD_STEP(eeC[1], ee0C[1]);
        FWD_STEP(eeC[2], ee0C[2]);
#undef FWD_STEP

        float Lacc = c0 + 0.6931471805599453f * (float)Eacc + __logf(Pm);
        ws[(size_t)b * CRF_N + lane] = Lacc + __logf(u * R);
    } else {
        // ================= BACKWARD: beta_{len-1} -> beta_127 =================
        // E'[j,k] = exp(tn[j,k]) (row-stochastic). This lane holds ROW j=lane.
        unsigned Rpk[32];
        #pragma unroll
        for (int m = 0; m < 32; ++m) {
            float e0 = __expf(trans[lane * CRF_N + 2 * m]     - rowlse_v);
            float e1 = __expf(trans[lane * CRF_N + 2 * m + 1] - rowlse_v);
            Rpk[m] = bf16_rne(e0) | (bf16_rne(e1) << 16);
        }

        // sequence length (dtype-adaptive: bool bytes vs int32)
        int len;
        {
            int c8 = 0;
            #pragma unroll
            for (int qq = 0; qq < 4; ++qq)
                c8 += (mask_u8[(size_t)b * CRF_T + qq * 64 + lane] != 0) ? 1 : 0;
            for (int off = 1; off < 64; off <<= 1) c8 += __shfl_xor(c8, off);
            if (c8 >= 128) {
                len = c8;
            } else {
                const int* mi = (const int*)mask_u8;
                int ci = 0;
                #pragma unroll
                for (int qq = 0; qq < 4; ++qq)
                    ci += (mi[(size_t)b * CRF_T + qq * 64 + lane] != 0) ? 1 : 0;
                for (int off = 1; off < 64; off <<= 1) ci += __shfl_xor(ci, off);
                len = ci;
            }
        }

        const float en = wave_lse(etrans[lane]);
        float etn = etrans[lane] - en;
        float c0 = rl0(etn);
        float w  = __expf(etn - c0);
        float R  = 1.0f, Pm = 1.0f;
        int   Eacc = 0;

        // step consumes emission at time t: y = w*exp(e_t); w' = (E' y) * R
#define BWD_STEP(EEB)                                                        \
        {                                                                    \
            float y = w * (EEB);                                             \
            unsigned upi = pack_pairs(y);                                    \
            float s = bdot64(upi, Rpk);                                      \
            float s0 = rl0(s);                                               \
            w = s * R;                                                       \
            float u0 = s0 * R;                                               \
            R = __builtin_amdgcn_rcpf(u0);                                   \
            Pm *= u0;                                                        \
        }

        int nb = len - 128;           // steps: t = len-1 down to 128
        int t  = len - 1;
        float eN[4], eeC[4];
        #pragma unroll
        for (int d = 0; d < 4; ++d) {
            int ti = t - d; ti = (ti >= 128) ? ti : 128;
            eN[d] = eb[(size_t)ti * CRF_N + lane];
        }
        #pragma unroll
        for (int d = 0; d < 4; ++d) eeC[d] = __expf(eN[d]);

        while (nb >= 4) {
            #pragma unroll
            for (int d = 0; d < 4; ++d) {
                int ti = t - 4 - d; ti = (ti >= 128) ? ti : 128;
                eN[d] = eb[(size_t)ti * CRF_N + lane];
            }
            BWD_STEP(eeC[0]); BWD_STEP(eeC[1]);
            BWD_STEP(eeC[2]); BWD_STEP(eeC[3]);
            { int ex; Pm = frexpf(Pm, &ex); Eacc += ex; }
            #pragma unroll
            for (int d = 0; d < 4; ++d) eeC[d] = __expf(eN[d]);
            t  -= 4;
            nb -= 4;
        }
        if (nb > 0) { BWD_STEP(eeC[0]); }
        if (nb > 1) { BWD_STEP(eeC[1]); }
        if (nb > 2) { BWD_STEP(eeC[2]); }
#undef BWD_STEP

        float Lacc = c0 + 0.6931471805599453f * (float)Eacc + __logf(Pm);
        ws[WS_BF_OFF + (size_t)b * CRF_N + lane] = Lacc + __logf(w * R);
    }
}

__launch_bounds__(64)
__global__ void crf_combine_kernel(const float* __restrict__ ws,
                                   float* __restrict__ out)
{
    const int lane = threadIdx.x;
    const int b    = blockIdx.x;
    float v = ws[(size_t)b * CRF_N + lane]
            + ws[WS_BF_OFF + (size_t)b * CRF_N + lane];
    float m = v;
    #pragma unroll
    for (int off = 1; off < 64; off <<= 1) m = fmaxf(m, __shfl_xor(m, off));
    float s = __expf(v - m);
    #pragma unroll
    for (int off = 1; off < 64; off <<= 1) s += __shfl_xor(s, off);
    if (lane == 0) atomicAdd(out, m + __logf(s));
}

extern "C" void kernel_launch(void* const* d_in, const int* in_sizes, int n_in,
                              void* d_out, int out_size, void* d_ws, size_t ws_size,
                              hipStream_t stream) {
    const float* emit   = (const float*)d_in[0];
    const float* trans  = (const float*)d_in[1];
    const float* strans = (const float*)d_in[2];
    const float* etrans = (const float*)d_in[3];
    const unsigned char* mask = (const unsigned char*)d_in[4];
    float* out = (float*)d_out;
    float* ws  = (float*)d_ws;

    hipMemsetAsync(out, 0, sizeof(float), stream);
    crf_fb_kernel<<<dim3(2 * CRF_B), dim3(64), 0, stream>>>(
        emit, trans, strans, etrans, mask, ws);
    crf_combine_kernel<<<dim3(CRF_B), dim3(64), 0, stream>>>(ws, out);
}